// Round 2
// baseline (1781.716 us; speedup 1.0000x reference)
//
#include <hip/hip_runtime.h>
#include <stdint.h>

// ---------------- problem constants ----------------
constexpr int kB  = 4;
constexpr int kT  = 2048;
constexpr int kH  = 2048;
constexpr int kI  = 8192;
constexpr int kTT = 256;           // decay window: exp(-0.2*256) ~ 6e-23 -> exact in f32
constexpr int kRows = kB * kT;     // 8192

typedef unsigned short u16;
typedef __bf16 bf16;
typedef bf16 bf16x8 __attribute__((ext_vector_type(8)));
typedef float f32x4 __attribute__((ext_vector_type(4)));

__device__ inline u16 f2b(float f) {           // f32 -> bf16 RNE
  union { float f; uint32_t u; } v; v.f = f;
  uint32_t r = v.u + 0x7FFFu + ((v.u >> 16) & 1u);
  return (u16)(r >> 16);
}
__device__ inline float b2f(u16 h) {
  union { uint32_t u; float f; } v; v.u = ((uint32_t)h) << 16;
  return v.f;
}

// ---------------- weight convert+transpose: f32 [R,C] -> bf16 [C,R] ----------------
__global__ void k_tconv(const float* __restrict__ src, u16* __restrict__ dst, int R, int C) {
  __shared__ float tile[32][33];
  int bc = blockIdx.x * 32, br = blockIdx.y * 32;
  int tx = threadIdx.x & 31, ty = threadIdx.x >> 5;  // 32 x 8
#pragma unroll
  for (int i = 0; i < 32; i += 8)
    tile[ty + i][tx] = src[(size_t)(br + ty + i) * C + bc + tx];
  __syncthreads();
#pragma unroll
  for (int i = 0; i < 32; i += 8)
    dst[(size_t)(bc + ty + i) * R + br + tx] = f2b(tile[tx][ty + i]);
}

// ---------------- block reduction (sum pair) over 256 threads ----------------
__device__ inline void bsum2(float& a, float& b, float* sbuf) {
#pragma unroll
  for (int off = 1; off < 64; off <<= 1) {
    a += __shfl_xor(a, off);
    b += __shfl_xor(b, off);
  }
  __syncthreads();  // protect sbuf from previous use
  int wid = threadIdx.x >> 6;
  if ((threadIdx.x & 63) == 0) { sbuf[wid] = a; sbuf[wid + 4] = b; }
  __syncthreads();
  a = sbuf[0] + sbuf[1] + sbuf[2] + sbuf[3];
  b = sbuf[4] + sbuf[5] + sbuf[6] + sbuf[7];
}

// ---------------- double LayerNorm: out = LN(LN(x;g1,b1);g2,b2) as bf16 ----------------
// WRITE_SHIFT: also write outs[row+1] = out[row] (within batch), outs[batch_row0] = 0
// BF16IN: x is bf16 (u16) instead of f32
template <int WRITE_SHIFT, int BF16IN>
__global__ void k_ln2(const void* __restrict__ xin,
                      const float* __restrict__ g1, const float* __restrict__ b1,
                      const float* __restrict__ g2, const float* __restrict__ b2,
                      u16* __restrict__ out, u16* __restrict__ outs) {
  __shared__ float sbuf[8];
  int row = blockIdx.x, tid = threadIdx.x;
  float v[8];
  if (BF16IN) {
    union { uint4 v4; u16 h[8]; } pu;
    pu.v4 = ((const uint4*)((const u16*)xin + (size_t)row * kH))[tid];
#pragma unroll
    for (int i = 0; i < 8; i++) v[i] = b2f(pu.h[i]);
  } else {
    const float4* xr = (const float4*)((const float*)xin + (size_t)row * kH);
    float4 t0 = xr[tid * 2], t1 = xr[tid * 2 + 1];
    v[0] = t0.x; v[1] = t0.y; v[2] = t0.z; v[3] = t0.w;
    v[4] = t1.x; v[5] = t1.y; v[6] = t1.z; v[7] = t1.w;
  }
  float s = 0.f, q = 0.f;
#pragma unroll
  for (int i = 0; i < 8; i++) { s += v[i]; q += v[i] * v[i]; }
  bsum2(s, q, sbuf);
  float m = s * (1.0f / kH);
  float rs = rsqrtf(q * (1.0f / kH) - m * m + 1e-12f);
  float y[8];
  s = 0.f; q = 0.f;
#pragma unroll
  for (int i = 0; i < 8; i++) {
    int c = tid * 8 + i;
    y[i] = (v[i] - m) * rs * g1[c] + b1[c];
    s += y[i]; q += y[i] * y[i];
  }
  bsum2(s, q, sbuf);
  m = s * (1.0f / kH);
  rs = rsqrtf(q * (1.0f / kH) - m * m + 1e-12f);
  union { uint4 v4; u16 h[8]; } pk;
#pragma unroll
  for (int i = 0; i < 8; i++) {
    int c = tid * 8 + i;
    pk.h[i] = f2b((y[i] - m) * rs * g2[c] + b2[c]);
  }
  ((uint4*)(out + (size_t)row * kH))[tid] = pk.v4;
  if (WRITE_SHIFT) {
    int t = row & (kT - 1);
    if (t < kT - 1) ((uint4*)(outs + (size_t)(row + 1) * kH))[tid] = pk.v4;
    if (t == 0) {
      uint4 z = {0, 0, 0, 0};
      ((uint4*)(outs + (size_t)row * kH))[tid] = z;
    }
  }
}

// ---------------- mix = tf*xln[t] + (1-tf)*xln[t-1]; also gather last kTT rows -> xv ----------------
__global__ void k_mix(const u16* __restrict__ xln, const float* __restrict__ tf,
                      u16* __restrict__ mix, u16* __restrict__ xv) {
  int row = blockIdx.x, tid = threadIdx.x;
  int t = row & (kT - 1), b = row >> 11;
  uint4 cur = ((const uint4*)(xln + (size_t)row * kH))[tid];
  uint4 prv = {0, 0, 0, 0};
  if (t > 0) prv = ((const uint4*)(xln + (size_t)(row - 1) * kH))[tid];
  union { uint4 v4; u16 h[8]; } cu, pu, pk;
  cu.v4 = cur; pu.v4 = prv;
#pragma unroll
  for (int i = 0; i < 8; i++) {
    int c = tid * 8 + i;
    float f = tf[c];
    pk.h[i] = f2b(b2f(cu.h[i]) * f + b2f(pu.h[i]) * (1.0f - f));
  }
  ((uint4*)(mix + (size_t)row * kH))[tid] = pk.v4;
  if (t >= kT - kTT) {
    size_t vrow = (size_t)b * kTT + (t - (kT - kTT));
    ((uint4*)(xv + vrow * kH))[tid] = cur;
  }
}

// ---------------- decay scan: vmix[b,c] = sum_s v[b,s,c]*e^(d_c*(kTT-1-s)) ----------------
__global__ void k_vmix(const float* __restrict__ v, const float* __restrict__ td,
                       float* __restrict__ vmix) {
  int c = blockIdx.x * 256 + threadIdx.x;
  int b = blockIdx.y;
  float ed = expf(td[c]);
  float acc = 0.f;
  const float* vp = v + (size_t)b * kTT * kH + c;
#pragma unroll 4
  for (int s = 0; s < kTT; s++) acc = acc * ed + vp[(size_t)s * kH];
  vmix[b * kH + c] = acc;
}

// ---------------- u[b,c] = vmix[b,:] @ Wo[:,c] + bo[c]  (tiny GEMM, f32) ----------------
__global__ void k_u(const float* __restrict__ vmix, const float* __restrict__ Wo,
                    const float* __restrict__ bo, float* __restrict__ u) {
  int c0 = blockIdx.x * 32;
  int col = threadIdx.x & 31, hg = threadIdx.x >> 5;  // 8 h-groups
  float acc[4] = {0.f, 0.f, 0.f, 0.f};
  for (int h = hg; h < kH; h += 8) {
    float w = Wo[(size_t)h * kH + c0 + col];
#pragma unroll
    for (int b = 0; b < 4; b++) acc[b] += vmix[b * kH + h] * w;
  }
  __shared__ float red[8][32][4];
#pragma unroll
  for (int b = 0; b < 4; b++) red[hg][col][b] = acc[b];
  __syncthreads();
  if (hg < 4) {
    int b = hg;
    float s = 0.f;
#pragma unroll
    for (int g = 0; g < 8; g++) s += red[g][col][b];
    u[b * kH + c0 + col] = s + bo[c0 + col];
  }
}

// ---------------- bf16 GEMM: C[M,N] = A[M,K] @ Bt[N,K]^T, fused epilogues ----------------
enum { EPI_F32 = 0, EPI_X2B = 1, EPI_RELU2 = 2, EPI_SIGB = 3, EPI_OUTB = 4 };

template <int EPI>
__global__ __launch_bounds__(256, 2) void gemm_bt(
    const u16* __restrict__ A, const u16* __restrict__ Bt, void* __restrict__ C,
    const void* __restrict__ e0, const void* __restrict__ e1, int M, int N, int K) {
  __shared__ alignas(16) u16 lA[128 * 32];
  __shared__ alignas(16) u16 lB[128 * 32];
  int nbm = M >> 7;
  int nbn = N >> 7;
  int G = (nbm & 7) ? 1 : 8;  // M-tile group for L2 reuse
  int bid = blockIdx.x;
  int grp = bid / (G * nbn), rem = bid % (G * nbn);
  int pm = grp * G + (rem % G);
  int pn = rem / G;
  size_t rowBase = (size_t)pm * 128, colBase = (size_t)pn * 128;

  int tid = threadIdx.x;
  int lane = tid & 63;
  int wid = tid >> 6;
  int wm = (wid >> 1) * 64, wn = (wid & 1) * 64;

  f32x4 acc[4][4] = {};

  // staging: thread t loads 16B at tile linear offset t*16 (rows of 64B)
  int arow = tid >> 2;
  int acol = (tid & 3) * 8;
  const u16* gA = A + (rowBase + arow) * (size_t)K + acol;
  const u16* gB = Bt + (colBase + arow) * (size_t)K + acol;
  u16* sA = (u16*)lA + tid * 8;
  u16* sB = (u16*)lB + tid * 8;
  int fr = lane & 15;
  int fk = (lane >> 4) * 8;

  for (int k0 = 0; k0 < K; k0 += 32) {
    __syncthreads();
    __builtin_amdgcn_global_load_lds((const __attribute__((address_space(1))) void*)(gA + k0),
                                     (__attribute__((address_space(3))) void*)sA, 16, 0, 0);
    __builtin_amdgcn_global_load_lds((const __attribute__((address_space(1))) void*)(gA + k0 + (size_t)64 * K),
                                     (__attribute__((address_space(3))) void*)(sA + 2048), 16, 0, 0);
    __builtin_amdgcn_global_load_lds((const __attribute__((address_space(1))) void*)(gB + k0),
                                     (__attribute__((address_space(3))) void*)sB, 16, 0, 0);
    __builtin_amdgcn_global_load_lds((const __attribute__((address_space(1))) void*)(gB + k0 + (size_t)64 * K),
                                     (__attribute__((address_space(3))) void*)(sB + 2048), 16, 0, 0);
    __syncthreads();
    bf16x8 af[4], bfr[4];
#pragma unroll
    for (int i = 0; i < 4; i++)
      af[i] = *(const bf16x8*)(lA + (wm + i * 16 + fr) * 32 + fk);
#pragma unroll
    for (int j = 0; j < 4; j++)
      bfr[j] = *(const bf16x8*)(lB + (wn + j * 16 + fr) * 32 + fk);
#pragma unroll
    for (int i = 0; i < 4; i++)
#pragma unroll
      for (int j = 0; j < 4; j++)
        acc[i][j] = __builtin_amdgcn_mfma_f32_16x16x32_bf16(af[i], bfr[j], acc[i][j], 0, 0, 0);
  }

  int frow = (lane >> 4) * 4;
  int fcol = lane & 15;
#pragma unroll
  for (int i = 0; i < 4; i++) {
#pragma unroll
    for (int j = 0; j < 4; j++) {
#pragma unroll
      for (int r = 0; r < 4; r++) {
        size_t gr = rowBase + wm + i * 16 + frow + r;
        size_t gc = colBase + wn + j * 16 + fcol;
        size_t idx = gr * (size_t)N + gc;
        float a = acc[i][j][r];
        if (EPI == EPI_F32) {
          ((float*)C)[idx] = a;
        } else if (EPI == EPI_X2B) {
          // x2 = bf16( x + sigmoid(a) * u[batch, col] )
          float sg = 1.0f / (1.0f + __expf(-a));
          size_t bidx = (gr >> 11) * (size_t)kH + gc;
          ((u16*)C)[idx] = f2b(((const float*)e0)[idx] + sg * ((const float*)e1)[bidx]);
        } else if (EPI == EPI_RELU2) {
          float t = fmaxf(a, 0.0f);
          ((u16*)C)[idx] = f2b(t * t);
        } else if (EPI == EPI_SIGB) {
          ((u16*)C)[idx] = f2b(1.0f / (1.0f + __expf(-a)));
        } else {  // EPI_OUTB: out = x2(bf16) + rc(bf16) * a
          ((float*)C)[idx] = b2f(((const u16*)e0)[idx]) + b2f(((const u16*)e1)[idx]) * a;
        }
      }
    }
  }
}

// ---------------- launcher ----------------
extern "C" void kernel_launch(void* const* d_in, const int* in_sizes, int n_in,
                              void* d_out, int out_size, void* d_ws, size_t ws_size,
                              hipStream_t stream) {
  const float* x      = (const float*)d_in[0];
  const float* ln1_g  = (const float*)d_in[1];
  const float* ln1_b  = (const float*)d_in[2];
  const float* ln2_g  = (const float*)d_in[3];
  const float* ln2_b  = (const float*)d_in[4];
  const float* tm_g   = (const float*)d_in[5];
  const float* tm_b   = (const float*)d_in[6];
  const float* tdec   = (const float*)d_in[7];
  const float* tfirst = (const float*)d_in[8];
  // d_in[9] = Wk: dead code in reference
  const float* Wv     = (const float*)d_in[10];
  const float* Wr     = (const float*)d_in[11];
  const float* Wo     = (const float*)d_in[12];
  const float* bo     = (const float*)d_in[13];
  const float* cm_g   = (const float*)d_in[14];
  const float* cm_b   = (const float*)d_in[15];
  const float* Wck    = (const float*)d_in[16];
  const float* Wcv    = (const float*)d_in[17];
  const float* Wcr    = (const float*)d_in[18];
  float* out = (float*)d_out;

  char* w = (char*)d_ws;
  size_t off = 0;
  auto alloc = [&](size_t bytes) -> char* {
    bytes = (bytes + 255) & ~(size_t)255;
    if (off + bytes > ws_size) off = 0;  // wrap guard: keeps pointers in-bounds (diagnostic)
    char* p = w + off;
    off += bytes;
    return p;
  };
  // lifetime-packed regions (aliases documented):
  u16* WA  = (u16*)alloc((size_t)kI * kH * 2);   // WckT; first 8 MiB doubles as W8 (WvT/WrT)
  u16* WB  = (u16*)alloc((size_t)kH * kI * 2);   // WcvT
  u16* WC  = (u16*)alloc((size_t)kH * kH * 2);   // WcrT
  u16* XLN = (u16*)alloc((size_t)kRows * kH * 2);// xln -> xc
  u16* MIX = (u16*)alloc((size_t)kRows * kH * 2);// mixb -> xcs
  u16* X2  = (u16*)alloc((size_t)kRows * kH * 2);// x2 bf16; first 8 MiB doubles as vbuf (f32)
  u16* XV  = (u16*)alloc((size_t)kB * kTT * kH * 2);
  float* vmixb = (float*)alloc((size_t)kB * kH * 4);
  float* ub    = (float*)alloc((size_t)kB * kH * 4);
  // adaptive channel-mixer chunk rows
  size_t avail = ws_size > off ? ws_size - off : 0;
  int Rc = 2048;
  while (Rc > 128 && ((size_t)Rc * (kI + kH) * 2 + 1024) > avail) Rc >>= 1;
  u16* KC  = (u16*)alloc((size_t)Rc * kI * 2);   // kc chunk (bf16)
  u16* RCc = (u16*)alloc((size_t)Rc * kH * 2);   // rc chunk (bf16)
  u16* W8 = WA;                                  // 8 MiB sub-slot of WA
  float* vbuf = (float*)X2;                      // 8 MiB sub-slot of X2

  // ---- time mixer ----
  k_tconv<<<dim3(kH / 32, kH / 32), 256, 0, stream>>>(Wv, W8, kH, kH);
  k_ln2<0, 0><<<kRows, 256, 0, stream>>>(x, ln1_g, ln1_b, tm_g, tm_b, XLN, nullptr);
  k_mix<<<kRows, 256, 0, stream>>>(XLN, tfirst, MIX, XV);
  gemm_bt<EPI_F32><<<(kB * kTT / 128) * (kH / 128), 256, 0, stream>>>(
      XV, W8, vbuf, nullptr, nullptr, kB * kTT, kH, kH);
  k_vmix<<<dim3(kH / 256, kB), 256, 0, stream>>>(vbuf, tdec, vmixb);
  k_u<<<kH / 32, 256, 0, stream>>>(vmixb, Wo, bo, ub);
  k_tconv<<<dim3(kH / 32, kH / 32), 256, 0, stream>>>(Wr, W8, kH, kH);  // vbuf consumed; W8 free
  gemm_bt<EPI_X2B><<<(kRows / 128) * (kH / 128), 256, 0, stream>>>(
      MIX, W8, X2, x, ub, kRows, kH, kH);

  // ---- channel mixer ----
  k_ln2<1, 1><<<kRows, 256, 0, stream>>>(X2, ln2_g, ln2_b, cm_g, cm_b, XLN /*xc*/, MIX /*xcs*/);
  k_tconv<<<dim3(kH / 32, kH / 32), 256, 0, stream>>>(Wcr, WC, kH, kH);
  k_tconv<<<dim3(kI / 32, kH / 32), 256, 0, stream>>>(Wck, WA, kH, kI);  // overwrites W8 (dead)
  k_tconv<<<dim3(kH / 32, kI / 32), 256, 0, stream>>>(Wcv, WB, kI, kH);

  int nch = kRows / Rc;
  for (int c = 0; c < nch; ++c) {
    size_t r0 = (size_t)c * Rc;
    // kc = relu(xcs @ Wck)^2  [bf16 chunk]
    gemm_bt<EPI_RELU2><<<(Rc / 128) * (kI / 128), 256, 0, stream>>>(
        MIX + r0 * kH, WA, KC, nullptr, nullptr, Rc, kI, kH);
    // rc = sigmoid(xc @ Wcr)  [bf16 chunk]
    gemm_bt<EPI_SIGB><<<(Rc / 128) * (kH / 128), 256, 0, stream>>>(
        XLN + r0 * kH, WC, RCc, nullptr, nullptr, Rc, kH, kH);
    // out = x2 + rc * (kc @ Wcv)
    gemm_bt<EPI_OUTB><<<(Rc / 128) * (kH / 128), 256, 0, stream>>>(
        KC, WB, out + r0 * kH, X2 + r0 * kH, RCc, Rc, kH, kI);
  }
}